// Round 1
// baseline (138.090 us; speedup 1.0000x reference)
//
#include <hip/hip_runtime.h>
#include <hip/hip_bf16.h>

// GCN layer, fused — R10: algebraic reorder  out = A·(X·W^T) + b
// (was out = (A·X)·W^T + b).  The dense projection moves into the prepass
// as a 16x128x128 MFMA GEMM (same memory cost as the old x->bf16 cast);
// the hot kernel becomes a pure gather + fp32-accumulate + coalesced store:
//   - deletes MFMA phase, agg_s LDS round-trip, 1 barrier, and the per-block
//     W fragment reads (32KB x 3125 blocks = 100MB L2 traffic) from main
//   - VGPR drops (no bfr/accum fragments) -> __launch_bounds__(256,7),
//     8-deep gather batch kept (fits ~73 VGPR without serialization)
//   - bias folded into the final store; out written directly in fp32
// Edge staging + quarter-wave-per-node SpMM structure unchanged (proven).

#define NPB     16
#define BLOCK   256
#define D       128
#define CHUNK   512
#define ASTRIDE 136   // LDS row stride in shorts (128 + 8 pad)

typedef __attribute__((ext_vector_type(8))) short bf16x8;
typedef __attribute__((ext_vector_type(4))) float f32x4;
typedef __attribute__((ext_vector_type(2))) float v2f;

__device__ __forceinline__ short f2bf(float f) {
    unsigned u = __float_as_uint(f);
    unsigned r = (u + 0x7fffu + ((u >> 16) & 1u)) >> 16;
    return (short)r;
}
__device__ __forceinline__ float bf_lo(int w) { return __int_as_float(w << 16); }
__device__ __forceinline__ float bf_hi(int w) { return __int_as_float(w & 0xffff0000); }

// ---------------- prepass: rs build + Yb = bf16(X @ W^T) ----------------
// Grid = gemm_blocks (16-node GEMM tiles) + search blocks (rs binary search).
__global__ __launch_bounds__(256, 4)
void prepass_kernel(const float* __restrict__ x,
                    const float* __restrict__ W,
                    const int*   __restrict__ edge_row,
                    short* __restrict__ yb,
                    int*   __restrict__ rs,
                    int n_nodes, int n_edges, int gemm_blocks)
{
    const int bid = blockIdx.x;
    const int tid = threadIdx.x;

    if (bid >= gemm_blocks) {
        // ---- rs binary-search blocks ----
        const int gid = (bid - gemm_blocks) * 256 + tid;
        if (gid <= n_nodes) {
            int lo = 0, hi = n_edges;
            while (lo < hi) {
                int mid = (lo + hi) >> 1;
                bool lt = (edge_row[mid] < gid);
                lo = lt ? (mid + 1) : lo;
                hi = lt ? hi : mid;
            }
            rs[gid] = lo;
        }
        return;
    }

    // ---- GEMM block: yb[tile] = bf16( x[tile] @ W^T ), tile = 16 nodes ----
    __shared__ __align__(16) short xa_s[NPB * ASTRIDE];   // 4.25 KB bf16

    const int wave = tid >> 6;
    const int lane = tid & 63;
    const int tile_base = bid * NPB;

    // stage x tile -> bf16 LDS (16 rows x 128 feats); 512 float4, 2/thread
    #pragma unroll
    for (int t = 0; t < 2; ++t) {
        int idx = tid * 2 + t;          // 0..511
        int row = idx >> 5;             // 32 float4 per row
        int c4  = idx & 31;
        int node = tile_base + row;
        float4 v = (node < n_nodes)
            ? reinterpret_cast<const float4*>(x)[(size_t)node * 32 + c4]
            : make_float4(0.f, 0.f, 0.f, 0.f);
        *reinterpret_cast<short4*>(&xa_s[row * ASTRIDE + c4 * 4]) =
            make_short4(f2bf(v.x), f2bf(v.y), f2bf(v.z), f2bf(v.w));
    }

    // B fragments straight from fp32 W ([j][k] row-major), convert in-reg
    const int n16 = lane & 15;
    const int g   = lane >> 4;

    bf16x8 bfr[2][4];
    #pragma unroll
    for (int tt = 0; tt < 2; ++tt) {
        const int jt = 2 * wave + tt;
        const float* wrow = W + (size_t)(jt * 16 + n16) * D + g * 8;
        #pragma unroll
        for (int ks = 0; ks < 4; ++ks) {
            float4 wa  = *reinterpret_cast<const float4*>(wrow + ks * 32);
            float4 wb4 = *reinterpret_cast<const float4*>(wrow + ks * 32 + 4);
            bf16x8 f;
            f[0] = f2bf(wa.x);  f[1] = f2bf(wa.y);  f[2] = f2bf(wa.z);  f[3] = f2bf(wa.w);
            f[4] = f2bf(wb4.x); f[5] = f2bf(wb4.y); f[6] = f2bf(wb4.z); f[7] = f2bf(wb4.w);
            bfr[tt][ks] = f;
        }
    }

    __syncthreads();

    // A fragments from LDS; MFMA layout identical to the verified R5-R8 phase-2
    bf16x8 afr[4];
    #pragma unroll
    for (int ks = 0; ks < 4; ++ks)
        afr[ks] = *reinterpret_cast<const bf16x8*>(&xa_s[n16 * ASTRIDE + ks * 32 + g * 8]);

    #pragma unroll
    for (int tt = 0; tt < 2; ++tt) {
        const int jt = 2 * wave + tt;
        const int j  = jt * 16 + n16;
        f32x4 c = {0.f, 0.f, 0.f, 0.f};
        #pragma unroll
        for (int ks = 0; ks < 4; ++ks)
            c = __builtin_amdgcn_mfma_f32_16x16x32_bf16(afr[ks], bfr[tt][ks], c, 0, 0, 0);
        #pragma unroll
        for (int r = 0; r < 4; ++r) {
            int node = tile_base + g * 4 + r;
            if (node < n_nodes)
                yb[(size_t)node * D + j] = f2bf(c[r]);   // no bias here
        }
    }
}

// ---------------- main kernel: out[i] = b + sum_e val[e] * Yb[col[e]] ----------------
__global__ __launch_bounds__(BLOCK, 7)
void gcn_main_kernel(const short* __restrict__ yb,
                     const int*   __restrict__ rs_g,
                     const int*   __restrict__ edge_col,
                     const float* __restrict__ edge_val,
                     const float* __restrict__ bvec,
                     float*       __restrict__ out,
                     int n_nodes, int n_edges)
{
    __shared__ int2 cv_s[CHUNK];          // 4 KB
    __shared__ int  rs_s[NPB + 1];

    const int tid  = threadIdx.x;
    const int wave = tid >> 6;
    const int lane = tid & 63;
    const int tile_base = blockIdx.x * NPB;

    // ---- Phase 0: row starts (one coalesced read) ----
    if (tid <= NPB) rs_s[tid] = rs_g[min(tile_base + tid, n_nodes)];
    __syncthreads();

    const int E0 = __builtin_amdgcn_readfirstlane(rs_s[0]);
    const int E1 = __builtin_amdgcn_readfirstlane(rs_s[NPB]);
    const int cnt = min(E1 - E0, CHUNK);

    // ---- stage the block's edge range once (tile degree ~256, <512 w.h.p.) ----
    for (int i = tid; i < cnt; i += BLOCK)
        cv_s[i] = make_int2(edge_col[E0 + i], __float_as_int(edge_val[E0 + i]));
    __syncthreads();

    // ---- quarter-wave-per-node gather + fp32 accumulate, 8-deep batches ----
    const int p = lane >> 4;              // quarter-wave id -> node within wave
    const int q = lane & 15;              // feature oct (8 bf16 = 16 B)
    const int n = wave * 4 + p;           // node within tile
    const int e0 = rs_s[n], e1 = rs_s[n + 1];
    const int cap  = E0 + cnt;
    const int ecap = min(e1, cap);
    const short* yq = yb + q * 8;

    v2f acc2[4];
    #pragma unroll
    for (int i = 0; i < 4; ++i) acc2[i] = (v2f){0.f, 0.f};

    for (int e = e0; e < ecap; e += 8) {
        int2 cv[8];
        int4 xr[8];
        // stage 1: 8 LDS metadata reads (broadcast within quarter-wave)
        #pragma unroll
        for (int u = 0; u < 8; ++u) {
            int idx = e + u;
            int il  = (idx < ecap) ? (idx - E0) : (e0 - E0);
            cv[u] = cv_s[il];
        }
        // stage 2: 8 gathers in flight
        #pragma unroll
        for (int u = 0; u < 8; ++u)
            xr[u] = *reinterpret_cast<const int4*>(yq + ((size_t)cv[u].x << 7));
        // stage 3: packed float2 FMA
        #pragma unroll
        for (int u = 0; u < 8; ++u) {
            float vm = (e + u < ecap) ? __int_as_float(cv[u].y) : 0.f;
            v2f v2 = (v2f){vm, vm};
            acc2[0] += v2 * (v2f){bf_lo(xr[u].x), bf_hi(xr[u].x)};
            acc2[1] += v2 * (v2f){bf_lo(xr[u].y), bf_hi(xr[u].y)};
            acc2[2] += v2 * (v2f){bf_lo(xr[u].z), bf_hi(xr[u].z)};
            acc2[3] += v2 * (v2f){bf_lo(xr[u].w), bf_hi(xr[u].w)};
        }
    }
    // cold slow path: only if tile degree exceeded CHUNK (never for this graph)
    for (int e = max(e0, cap); e < e1; ++e) {
        int   c = edge_col[e];
        float v = edge_val[e];
        int4 xr = *reinterpret_cast<const int4*>(yq + ((size_t)c << 7));
        v2f v2 = (v2f){v, v};
        acc2[0] += v2 * (v2f){bf_lo(xr.x), bf_hi(xr.x)};
        acc2[1] += v2 * (v2f){bf_lo(xr.y), bf_hi(xr.y)};
        acc2[2] += v2 * (v2f){bf_lo(xr.z), bf_hi(xr.z)};
        acc2[3] += v2 * (v2f){bf_lo(xr.w), bf_hi(xr.w)};
    }

    // ---- bias + direct coalesced fp32 store (512B contiguous per node) ----
    const int node = tile_base + n;
    if (node < n_nodes) {
        const float* bq = bvec + q * 8;
        float4 b0 = *reinterpret_cast<const float4*>(bq);
        float4 b1 = *reinterpret_cast<const float4*>(bq + 4);
        float* orow = out + (size_t)node * D + q * 8;
        float4 o0 = make_float4(acc2[0].x + b0.x, acc2[0].y + b0.y,
                                acc2[1].x + b0.z, acc2[1].y + b0.w);
        float4 o1 = make_float4(acc2[2].x + b1.x, acc2[2].y + b1.y,
                                acc2[3].x + b1.z, acc2[3].y + b1.w);
        *reinterpret_cast<float4*>(orow)     = o0;
        *reinterpret_cast<float4*>(orow + 4) = o1;
    }
}

// ---------------- fallback (R5 kernel, fp32 gathers, no ws) ----------------
__global__ __launch_bounds__(BLOCK, 5)
void gcn_fallback_kernel(const float* __restrict__ x,
                         const int*   __restrict__ edge_row,
                         const int*   __restrict__ edge_col,
                         const float* __restrict__ edge_val,
                         const float* __restrict__ W,
                         const float* __restrict__ bvec,
                         float*       __restrict__ out,
                         int n_nodes, int n_edges)
{
    __shared__ __align__(16) short agg_s[NPB * ASTRIDE];
    __shared__ int rs_s[NPB + 1];

    const int tid  = threadIdx.x;
    const int wave = tid >> 6;
    const int lane = tid & 63;
    const int tile_base = blockIdx.x * NPB;

    if (tid <= NPB) {
        int target = tile_base + tid;
        if (target > n_nodes) target = n_nodes;
        int lo = 0, hi = n_edges;
        while (lo < hi) {
            int mid = (lo + hi) >> 1;
            lo = (edge_row[mid] < target) ? (mid + 1) : lo;
            hi = (edge_row[mid] < target) ? hi : mid;
        }
        rs_s[tid] = lo;
    }
    __syncthreads();

    {
        const int h = lane >> 5;
        const int q = lane & 31;
        const float* xq = x + (q << 2);

        #pragma unroll
        for (int ni = 0; ni < NPB / 4; ++ni) {
            const int n = wave + 4 * ni;
            const int e0 = __builtin_amdgcn_readfirstlane(rs_s[n]);
            const int e1 = __builtin_amdgcn_readfirstlane(rs_s[n + 1]);
            float ax = 0.f, ay = 0.f, az = 0.f, aw = 0.f;
            for (int e = e0; e < e1; e += 16) {
                #pragma unroll
                for (int u = 0; u < 8; ++u) {
                    int idx  = e + 2 * u + h;
                    int idxc = (idx < e1) ? idx : (e1 - 1);
                    int   c  = edge_col[idxc];
                    float vr = edge_val[idxc];
                    float v  = (idx < e1) ? vr : 0.f;
                    float4 xr = *reinterpret_cast<const float4*>(xq + ((size_t)c << 7));
                    ax += v * xr.x; ay += v * xr.y; az += v * xr.z; aw += v * xr.w;
                }
            }
            ax += __shfl_xor(ax, 32, 64); ay += __shfl_xor(ay, 32, 64);
            az += __shfl_xor(az, 32, 64); aw += __shfl_xor(aw, 32, 64);
            if (h == 0) {
                *reinterpret_cast<short4*>(&agg_s[n * ASTRIDE + (q << 2)]) =
                    make_short4(f2bf(ax), f2bf(ay), f2bf(az), f2bf(aw));
            }
        }
    }

    const int n16 = lane & 15;
    const int g   = lane >> 4;
    bf16x8 bfr[2][4];
    #pragma unroll
    for (int tt = 0; tt < 2; ++tt) {
        const int jt = 2 * wave + tt;
        const float* rowp = W + ((size_t)(jt * 16 + n16)) * D + g * 8;
        #pragma unroll
        for (int ks = 0; ks < 4; ++ks) {
            float4 wa  = *reinterpret_cast<const float4*>(rowp + ks * 32);
            float4 wb4 = *reinterpret_cast<const float4*>(rowp + ks * 32 + 4);
            bf16x8 f;
            f[0] = f2bf(wa.x);  f[1] = f2bf(wa.y);  f[2] = f2bf(wa.z);  f[3] = f2bf(wa.w);
            f[4] = f2bf(wb4.x); f[5] = f2bf(wb4.y); f[6] = f2bf(wb4.z); f[7] = f2bf(wb4.w);
            bfr[tt][ks] = f;
        }
    }
    __syncthreads();
    {
        bf16x8 afr[4];
        #pragma unroll
        for (int ks = 0; ks < 4; ++ks)
            afr[ks] = *reinterpret_cast<const bf16x8*>(&agg_s[n16 * ASTRIDE + ks * 32 + g * 8]);
        #pragma unroll
        for (int tt = 0; tt < 2; ++tt) {
            const int jt = 2 * wave + tt;
            const int j  = jt * 16 + n16;
            const float bj = bvec[j];
            f32x4 c = {0.f, 0.f, 0.f, 0.f};
            #pragma unroll
            for (int ks = 0; ks < 4; ++ks)
                c = __builtin_amdgcn_mfma_f32_16x16x32_bf16(afr[ks], bfr[tt][ks], c, 0, 0, 0);
            #pragma unroll
            for (int r = 0; r < 4; ++r) {
                int node = tile_base + g * 4 + r;
                if (node < n_nodes)
                    out[(size_t)node * D + j] = c[r] + bj;
            }
        }
    }
}

extern "C" void kernel_launch(void* const* d_in, const int* in_sizes, int n_in,
                              void* d_out, int out_size, void* d_ws, size_t ws_size,
                              hipStream_t stream) {
    const float* x        = (const float*)d_in[0];
    const int*   edge_row = (const int*)  d_in[1];
    const int*   edge_col = (const int*)  d_in[2];
    const float* edge_val = (const float*)d_in[3];
    const float* W        = (const float*)d_in[4];
    const float* b        = (const float*)d_in[5];
    float* out = (float*)d_out;

    const int n_nodes = in_sizes[0] / D;
    const int n_edges = in_sizes[1];
    const int grid = (n_nodes + NPB - 1) / NPB;

    const size_t yb_bytes = (size_t)n_nodes * D * sizeof(short);
    const size_t rs_bytes = (size_t)(n_nodes + 1) * sizeof(int);
    if (ws_size >= yb_bytes + rs_bytes) {
        short* yb = (short*)d_ws;
        int*   rs = (int*)((char*)d_ws + yb_bytes);
        const int gemm_blocks   = grid;                       // 16 nodes each
        const int search_blocks = (n_nodes + 1 + 255) / 256;  // rs entries
        prepass_kernel<<<gemm_blocks + search_blocks, 256, 0, stream>>>(
            x, W, edge_row, yb, rs, n_nodes, n_edges, gemm_blocks);
        gcn_main_kernel<<<grid, BLOCK, 0, stream>>>(yb, rs, edge_col, edge_val,
                                                    b, out, n_nodes, n_edges);
    } else {
        gcn_fallback_kernel<<<grid, BLOCK, 0, stream>>>(x, edge_row, edge_col, edge_val,
                                                        W, b, out, n_nodes, n_edges);
    }
}

// Round 2
// 124.975 us; speedup vs baseline: 1.1049x; 1.1049x over previous
//
#include <hip/hip_runtime.h>
#include <hip/hip_bf16.h>

// GCN layer, fused — R11: keep R10's algebraic reorder out = A·(X·W^T) + b,
// fix the two R10 regressions:
//  (1) main kernel back to __launch_bounds__(256,6): (256,7) capped VGPR at
//      ~73 and re-serialized/spilled the 8-deep gather batch (R8 failure mode;
//      R9's proven budget is ~85 VGPR at 6 waves/SIMD).
//  (2) prepass GEMM now 64 nodes/block (4 sub-tiles share one W-fragment
//      load): 782 blocks instead of 3125, 4x less W L2 re-read (200->50MB),
//      4x better amortization of barriers + per-block fixed cost.
// Main kernel is the pure gather + fp32 accumulate + coalesced fp32 store.

#define NPB     16    // nodes per main-kernel block
#define NPP     64    // nodes per prepass GEMM block (4 sub-tiles of 16)
#define BLOCK   256
#define D       128
#define CHUNK   512
#define ASTRIDE 136   // LDS row stride in shorts (128 + 8 pad)

typedef __attribute__((ext_vector_type(8))) short bf16x8;
typedef __attribute__((ext_vector_type(4))) float f32x4;
typedef __attribute__((ext_vector_type(2))) float v2f;

__device__ __forceinline__ short f2bf(float f) {
    unsigned u = __float_as_uint(f);
    unsigned r = (u + 0x7fffu + ((u >> 16) & 1u)) >> 16;
    return (short)r;
}
__device__ __forceinline__ float bf_lo(int w) { return __int_as_float(w << 16); }
__device__ __forceinline__ float bf_hi(int w) { return __int_as_float(w & 0xffff0000); }

// ---------------- prepass: rs build + Yb = bf16(X @ W^T) ----------------
// Grid = gemm_blocks (64-node GEMM tiles) + search blocks (rs binary search).
__global__ __launch_bounds__(256, 4)
void prepass_kernel(const float* __restrict__ x,
                    const float* __restrict__ W,
                    const int*   __restrict__ edge_row,
                    short* __restrict__ yb,
                    int*   __restrict__ rs,
                    int n_nodes, int n_edges, int gemm_blocks)
{
    const int bid = blockIdx.x;
    const int tid = threadIdx.x;

    if (bid >= gemm_blocks) {
        // ---- rs binary-search blocks ----
        const int gid = (bid - gemm_blocks) * 256 + tid;
        if (gid <= n_nodes) {
            int lo = 0, hi = n_edges;
            while (lo < hi) {
                int mid = (lo + hi) >> 1;
                bool lt = (edge_row[mid] < gid);
                lo = lt ? (mid + 1) : lo;
                hi = lt ? hi : mid;
            }
            rs[gid] = lo;
        }
        return;
    }

    // ---- GEMM block: yb[64-node tile] = bf16( x @ W^T ) ----
    __shared__ __align__(16) short xa_s[NPP * ASTRIDE];   // 17.0 KB bf16

    const int wave = tid >> 6;
    const int lane = tid & 63;
    const int tile_base = bid * NPP;

    // stage x tile -> bf16 LDS (64 rows x 128 feats); 2048 float4, 8/thread,
    // fully coalesced (idx consecutive across threads each iteration)
    #pragma unroll
    for (int t = 0; t < 8; ++t) {
        int idx = t * 256 + tid;        // 0..2047
        int row = idx >> 5;             // 32 float4 per row
        int c4  = idx & 31;
        int node = tile_base + row;
        float4 v = (node < n_nodes)
            ? reinterpret_cast<const float4*>(x)[(size_t)node * 32 + c4]
            : make_float4(0.f, 0.f, 0.f, 0.f);
        *reinterpret_cast<short4*>(&xa_s[row * ASTRIDE + c4 * 4]) =
            make_short4(f2bf(v.x), f2bf(v.y), f2bf(v.z), f2bf(v.w));
    }

    // B fragments straight from fp32 W ([j][k] row-major), convert in-reg.
    // Loaded ONCE, reused by all 4 sub-tiles.
    const int n16 = lane & 15;
    const int g   = lane >> 4;

    bf16x8 bfr[2][4];
    #pragma unroll
    for (int tt = 0; tt < 2; ++tt) {
        const int jt = 2 * wave + tt;
        const float* wrow = W + (size_t)(jt * 16 + n16) * D + g * 8;
        #pragma unroll
        for (int ks = 0; ks < 4; ++ks) {
            float4 wa  = *reinterpret_cast<const float4*>(wrow + ks * 32);
            float4 wb4 = *reinterpret_cast<const float4*>(wrow + ks * 32 + 4);
            bf16x8 f;
            f[0] = f2bf(wa.x);  f[1] = f2bf(wa.y);  f[2] = f2bf(wa.z);  f[3] = f2bf(wa.w);
            f[4] = f2bf(wb4.x); f[5] = f2bf(wb4.y); f[6] = f2bf(wb4.z); f[7] = f2bf(wb4.w);
            bfr[tt][ks] = f;
        }
    }

    __syncthreads();

    // 4 sub-tiles of 16 nodes; MFMA layout identical to verified R5-R8 phase-2
    #pragma unroll
    for (int st = 0; st < 4; ++st) {
        const int rbase = st * 16;
        bf16x8 afr[4];
        #pragma unroll
        for (int ks = 0; ks < 4; ++ks)
            afr[ks] = *reinterpret_cast<const bf16x8*>(
                &xa_s[(rbase + n16) * ASTRIDE + ks * 32 + g * 8]);

        #pragma unroll
        for (int tt = 0; tt < 2; ++tt) {
            const int jt = 2 * wave + tt;
            const int j  = jt * 16 + n16;
            f32x4 c = {0.f, 0.f, 0.f, 0.f};
            #pragma unroll
            for (int ks = 0; ks < 4; ++ks)
                c = __builtin_amdgcn_mfma_f32_16x16x32_bf16(afr[ks], bfr[tt][ks], c, 0, 0, 0);
            #pragma unroll
            for (int r = 0; r < 4; ++r) {
                int node = tile_base + rbase + g * 4 + r;
                if (node < n_nodes)
                    yb[(size_t)node * D + j] = f2bf(c[r]);   // no bias here
            }
        }
    }
}

// ---------------- main kernel: out[i] = b + sum_e val[e] * Yb[col[e]] ----------------
__global__ __launch_bounds__(BLOCK, 6)
void gcn_main_kernel(const short* __restrict__ yb,
                     const int*   __restrict__ rs_g,
                     const int*   __restrict__ edge_col,
                     const float* __restrict__ edge_val,
                     const float* __restrict__ bvec,
                     float*       __restrict__ out,
                     int n_nodes, int n_edges)
{
    __shared__ int2 cv_s[CHUNK];          // 4 KB
    __shared__ int  rs_s[NPB + 1];

    const int tid  = threadIdx.x;
    const int wave = tid >> 6;
    const int lane = tid & 63;
    const int tile_base = blockIdx.x * NPB;

    // ---- Phase 0: row starts (one coalesced read) ----
    if (tid <= NPB) rs_s[tid] = rs_g[min(tile_base + tid, n_nodes)];
    __syncthreads();

    const int E0 = __builtin_amdgcn_readfirstlane(rs_s[0]);
    const int E1 = __builtin_amdgcn_readfirstlane(rs_s[NPB]);
    const int cnt = min(E1 - E0, CHUNK);

    // ---- stage the block's edge range once (tile degree ~256, <512 w.h.p.) ----
    for (int i = tid; i < cnt; i += BLOCK)
        cv_s[i] = make_int2(edge_col[E0 + i], __float_as_int(edge_val[E0 + i]));
    __syncthreads();

    // ---- quarter-wave-per-node gather + fp32 accumulate, 8-deep batches ----
    const int p = lane >> 4;              // quarter-wave id -> node within wave
    const int q = lane & 15;              // feature oct (8 bf16 = 16 B)
    const int n = wave * 4 + p;           // node within tile
    const int e0 = rs_s[n], e1 = rs_s[n + 1];
    const int cap  = E0 + cnt;
    const int ecap = min(e1, cap);
    const short* yq = yb + q * 8;

    v2f acc2[4];
    #pragma unroll
    for (int i = 0; i < 4; ++i) acc2[i] = (v2f){0.f, 0.f};

    for (int e = e0; e < ecap; e += 8) {
        int2 cv[8];
        int4 xr[8];
        // stage 1: 8 LDS metadata reads (broadcast within quarter-wave)
        #pragma unroll
        for (int u = 0; u < 8; ++u) {
            int idx = e + u;
            int il  = (idx < ecap) ? (idx - E0) : (e0 - E0);
            cv[u] = cv_s[il];
        }
        // stage 2: 8 gathers in flight
        #pragma unroll
        for (int u = 0; u < 8; ++u)
            xr[u] = *reinterpret_cast<const int4*>(yq + ((size_t)cv[u].x << 7));
        // stage 3: packed float2 FMA
        #pragma unroll
        for (int u = 0; u < 8; ++u) {
            float vm = (e + u < ecap) ? __int_as_float(cv[u].y) : 0.f;
            v2f v2 = (v2f){vm, vm};
            acc2[0] += v2 * (v2f){bf_lo(xr[u].x), bf_hi(xr[u].x)};
            acc2[1] += v2 * (v2f){bf_lo(xr[u].y), bf_hi(xr[u].y)};
            acc2[2] += v2 * (v2f){bf_lo(xr[u].z), bf_hi(xr[u].z)};
            acc2[3] += v2 * (v2f){bf_lo(xr[u].w), bf_hi(xr[u].w)};
        }
    }
    // cold slow path: only if tile degree exceeded CHUNK (never for this graph)
    for (int e = max(e0, cap); e < e1; ++e) {
        int   c = edge_col[e];
        float v = edge_val[e];
        int4 xr = *reinterpret_cast<const int4*>(yq + ((size_t)c << 7));
        v2f v2 = (v2f){v, v};
        acc2[0] += v2 * (v2f){bf_lo(xr.x), bf_hi(xr.x)};
        acc2[1] += v2 * (v2f){bf_lo(xr.y), bf_hi(xr.y)};
        acc2[2] += v2 * (v2f){bf_lo(xr.z), bf_hi(xr.z)};
        acc2[3] += v2 * (v2f){bf_lo(xr.w), bf_hi(xr.w)};
    }

    // ---- bias + direct coalesced fp32 store (512B contiguous per node) ----
    const int node = tile_base + n;
    if (node < n_nodes) {
        const float* bq = bvec + q * 8;
        float4 b0 = *reinterpret_cast<const float4*>(bq);
        float4 b1 = *reinterpret_cast<const float4*>(bq + 4);
        float* orow = out + (size_t)node * D + q * 8;
        float4 o0 = make_float4(acc2[0].x + b0.x, acc2[0].y + b0.y,
                                acc2[1].x + b0.z, acc2[1].y + b0.w);
        float4 o1 = make_float4(acc2[2].x + b1.x, acc2[2].y + b1.y,
                                acc2[3].x + b1.z, acc2[3].y + b1.w);
        *reinterpret_cast<float4*>(orow)     = o0;
        *reinterpret_cast<float4*>(orow + 4) = o1;
    }
}

// ---------------- fallback (R5 kernel, fp32 gathers, no ws) ----------------
__global__ __launch_bounds__(BLOCK, 5)
void gcn_fallback_kernel(const float* __restrict__ x,
                         const int*   __restrict__ edge_row,
                         const int*   __restrict__ edge_col,
                         const float* __restrict__ edge_val,
                         const float* __restrict__ W,
                         const float* __restrict__ bvec,
                         float*       __restrict__ out,
                         int n_nodes, int n_edges)
{
    __shared__ __align__(16) short agg_s[NPB * ASTRIDE];
    __shared__ int rs_s[NPB + 1];

    const int tid  = threadIdx.x;
    const int wave = tid >> 6;
    const int lane = tid & 63;
    const int tile_base = blockIdx.x * NPB;

    if (tid <= NPB) {
        int target = tile_base + tid;
        if (target > n_nodes) target = n_nodes;
        int lo = 0, hi = n_edges;
        while (lo < hi) {
            int mid = (lo + hi) >> 1;
            lo = (edge_row[mid] < target) ? (mid + 1) : lo;
            hi = (edge_row[mid] < target) ? hi : mid;
        }
        rs_s[tid] = lo;
    }
    __syncthreads();

    {
        const int h = lane >> 5;
        const int q = lane & 31;
        const float* xq = x + (q << 2);

        #pragma unroll
        for (int ni = 0; ni < NPB / 4; ++ni) {
            const int n = wave + 4 * ni;
            const int e0 = __builtin_amdgcn_readfirstlane(rs_s[n]);
            const int e1 = __builtin_amdgcn_readfirstlane(rs_s[n + 1]);
            float ax = 0.f, ay = 0.f, az = 0.f, aw = 0.f;
            for (int e = e0; e < e1; e += 16) {
                #pragma unroll
                for (int u = 0; u < 8; ++u) {
                    int idx  = e + 2 * u + h;
                    int idxc = (idx < e1) ? idx : (e1 - 1);
                    int   c  = edge_col[idxc];
                    float vr = edge_val[idxc];
                    float v  = (idx < e1) ? vr : 0.f;
                    float4 xr = *reinterpret_cast<const float4*>(xq + ((size_t)c << 7));
                    ax += v * xr.x; ay += v * xr.y; az += v * xr.z; aw += v * xr.w;
                }
            }
            ax += __shfl_xor(ax, 32, 64); ay += __shfl_xor(ay, 32, 64);
            az += __shfl_xor(az, 32, 64); aw += __shfl_xor(aw, 32, 64);
            if (h == 0) {
                *reinterpret_cast<short4*>(&agg_s[n * ASTRIDE + (q << 2)]) =
                    make_short4(f2bf(ax), f2bf(ay), f2bf(az), f2bf(aw));
            }
        }
    }

    const int n16 = lane & 15;
    const int g   = lane >> 4;
    bf16x8 bfr[2][4];
    #pragma unroll
    for (int tt = 0; tt < 2; ++tt) {
        const int jt = 2 * wave + tt;
        const float* rowp = W + ((size_t)(jt * 16 + n16)) * D + g * 8;
        #pragma unroll
        for (int ks = 0; ks < 4; ++ks) {
            float4 wa  = *reinterpret_cast<const float4*>(rowp + ks * 32);
            float4 wb4 = *reinterpret_cast<const float4*>(rowp + ks * 32 + 4);
            bf16x8 f;
            f[0] = f2bf(wa.x);  f[1] = f2bf(wa.y);  f[2] = f2bf(wa.z);  f[3] = f2bf(wa.w);
            f[4] = f2bf(wb4.x); f[5] = f2bf(wb4.y); f[6] = f2bf(wb4.z); f[7] = f2bf(wb4.w);
            bfr[tt][ks] = f;
        }
    }
    __syncthreads();
    {
        bf16x8 afr[4];
        #pragma unroll
        for (int ks = 0; ks < 4; ++ks)
            afr[ks] = *reinterpret_cast<const bf16x8*>(&agg_s[n16 * ASTRIDE + ks * 32 + g * 8]);
        #pragma unroll
        for (int tt = 0; tt < 2; ++tt) {
            const int jt = 2 * wave + tt;
            const int j  = jt * 16 + n16;
            const float bj = bvec[j];
            f32x4 c = {0.f, 0.f, 0.f, 0.f};
            #pragma unroll
            for (int ks = 0; ks < 4; ++ks)
                c = __builtin_amdgcn_mfma_f32_16x16x32_bf16(afr[ks], bfr[tt][ks], c, 0, 0, 0);
            #pragma unroll
            for (int r = 0; r < 4; ++r) {
                int node = tile_base + g * 4 + r;
                if (node < n_nodes)
                    out[(size_t)node * D + j] = c[r] + bj;
            }
        }
    }
}

extern "C" void kernel_launch(void* const* d_in, const int* in_sizes, int n_in,
                              void* d_out, int out_size, void* d_ws, size_t ws_size,
                              hipStream_t stream) {
    const float* x        = (const float*)d_in[0];
    const int*   edge_row = (const int*)  d_in[1];
    const int*   edge_col = (const int*)  d_in[2];
    const float* edge_val = (const float*)d_in[3];
    const float* W        = (const float*)d_in[4];
    const float* b        = (const float*)d_in[5];
    float* out = (float*)d_out;

    const int n_nodes = in_sizes[0] / D;
    const int n_edges = in_sizes[1];
    const int grid = (n_nodes + NPB - 1) / NPB;

    const size_t yb_bytes = (size_t)n_nodes * D * sizeof(short);
    const size_t rs_bytes = (size_t)(n_nodes + 1) * sizeof(int);
    if (ws_size >= yb_bytes + rs_bytes) {
        short* yb = (short*)d_ws;
        int*   rs = (int*)((char*)d_ws + yb_bytes);
        const int gemm_blocks   = (n_nodes + NPP - 1) / NPP;  // 64 nodes each
        const int search_blocks = (n_nodes + 1 + 255) / 256;  // rs entries
        prepass_kernel<<<gemm_blocks + search_blocks, 256, 0, stream>>>(
            x, W, edge_row, yb, rs, n_nodes, n_edges, gemm_blocks);
        gcn_main_kernel<<<grid, BLOCK, 0, stream>>>(yb, rs, edge_col, edge_val,
                                                    b, out, n_nodes, n_edges);
    } else {
        gcn_fallback_kernel<<<grid, BLOCK, 0, stream>>>(x, edge_row, edge_col, edge_val,
                                                        W, b, out, n_nodes, n_edges);
    }
}